// Round 4
// baseline (244.601 us; speedup 1.0000x reference)
//
#include <hip/hip_runtime.h>

#define N_NODES 40000
#define N_EDGES 640000
#define HD 128
#define N_REL2 474
#define BN_EPS 1e-5f
#define NB_SCAN ((N_NODES + 255) / 256)  // 157 scan blocks

// ---- float <-> monotone-ordered uint mapping (for atomicMax on floats) ----
__device__ __forceinline__ unsigned fmap(float f) {
    unsigned u = __float_as_uint(f);
    return (u & 0x80000000u) ? ~u : (u | 0x80000000u);
}
__device__ __forceinline__ float funmap(unsigned u) {
    return (u & 0x80000000u) ? __uint_as_float(u ^ 0x80000000u)
                             : __uint_as_float(~u);
}

// K1: histogram of edge destinations
__global__ __launch_bounds__(256) void k_hist(
        const int* __restrict__ dst, int* __restrict__ counts) {
    int e = blockIdx.x * 256 + threadIdx.x;
    if (e < N_EDGES) atomicAdd(counts + dst[e], 1);
}

// K2a: per-block sum of 256 counts
__global__ __launch_bounds__(256) void k_scan_part(
        const int* __restrict__ counts, int* __restrict__ bsum) {
    __shared__ int ls[256];
    int t = threadIdx.x;
    int idx = blockIdx.x * 256 + t;
    ls[t] = (idx < N_NODES) ? counts[idx] : 0;
    __syncthreads();
    #pragma unroll
    for (int off = 128; off > 0; off >>= 1) {
        if (t < off) ls[t] += ls[t + off];
        __syncthreads();
    }
    if (t == 0) bsum[blockIdx.x] = ls[0];
}

// K2b: single tiny block — exclusive scan of NB_SCAN block sums in place
__global__ __launch_bounds__(256) void k_scan_top(int* __restrict__ bsum) {
    __shared__ int ls[256];
    int t = threadIdx.x;
    int v = (t < NB_SCAN) ? bsum[t] : 0;
    ls[t] = v;
    __syncthreads();
    #pragma unroll
    for (int off = 1; off < 256; off <<= 1) {
        int tmp = (t >= off) ? ls[t - off] : 0;
        __syncthreads();
        ls[t] += tmp;
        __syncthreads();
    }
    if (t < NB_SCAN) bsum[t] = ls[t] - v;  // exclusive
}

// K2c: per-block local exclusive scan + block offset -> row_off, cursor
__global__ __launch_bounds__(256) void k_scan_down(
        const int* __restrict__ counts, const int* __restrict__ bsum,
        int* __restrict__ row_off, int* __restrict__ cursor) {
    __shared__ int ls[256];
    int t = threadIdx.x;
    int idx = blockIdx.x * 256 + t;
    int v = (idx < N_NODES) ? counts[idx] : 0;
    ls[t] = v;
    __syncthreads();
    #pragma unroll
    for (int off = 1; off < 256; off <<= 1) {
        int tmp = (t >= off) ? ls[t - off] : 0;
        __syncthreads();
        ls[t] += tmp;
        __syncthreads();
    }
    int excl = ls[t] - v + bsum[blockIdx.x];
    if (idx < N_NODES) {
        row_off[idx] = excl;
        cursor[idx] = excl;
    }
    if (idx == N_NODES) row_off[N_NODES] = N_EDGES;
}

// K3: scatter rel ids + node ids into CSR order
__global__ __launch_bounds__(256) void k_sortrel(
        const int* __restrict__ dst, const int* __restrict__ rel_id,
        int* __restrict__ cursor, int* __restrict__ sorted_rel,
        int* __restrict__ sorted_node) {
    int e = blockIdx.x * 256 + threadIdx.x;
    if (e < N_EDGES) {
        int d = dst[e];
        int p = atomicAdd(cursor + d, 1);
        sorted_rel[p] = rel_id[e];
        sorted_node[p] = d;
    }
}

// K4: RW = rel_emb @ neigh_w  (474 x 128 @ 128 x 128)
__global__ __launch_bounds__(128) void k_rw(
        const float* __restrict__ R, const float* __restrict__ W,
        float* __restrict__ RW) {
    __shared__ float row[HD];
    int r = blockIdx.x, c = threadIdx.x;
    row[c] = R[(size_t)r * HD + c];
    __syncthreads();
    float acc = 0.f;
    #pragma unroll 8
    for (int k = 0; k < HD; ++k) acc += row[k] * W[(size_t)k * HD + c];
    RW[(size_t)r * HD + c] = acc;
}

// K5: per-sorted-edge dot (32 lanes/edge) + atomicMax smax[node]
//     CSR order => consecutive edges share the ent_emb row (L1 hits)
__global__ __launch_bounds__(256) void k_edge_dot(
        const float* __restrict__ ent_emb, const float* __restrict__ R,
        const int* __restrict__ sorted_rel, const int* __restrict__ sorted_node,
        float* __restrict__ sorted_s, unsigned* __restrict__ smax_u) {
    int t = threadIdx.x;
    int e = blockIdx.x * 8 + (t >> 5);
    if (e >= N_EDGES) return;
    int lane = t & 31;
    int r = sorted_rel[e], n = sorted_node[e];
    float4 a = ((const float4*)(R + (size_t)r * HD))[lane];
    float4 b = ((const float4*)(ent_emb + (size_t)n * HD))[lane];
    float dot = a.x * b.x + a.y * b.y + a.z * b.z + a.w * b.w;
    #pragma unroll
    for (int m = 16; m >= 1; m >>= 1) dot += __shfl_xor(dot, m, 32);
    if (lane == 0) {
        sorted_s[e] = dot;
        atomicMax(smax_u + n, fmap(dot));
    }
}

// K6: per-node weighted sum: h[n] = sum_i exp(s_i - smax) * RW[r_i] / l
//     branch-free, shuffle-free; loads pipeline freely
__global__ __launch_bounds__(256) void k_node(
        const float* __restrict__ RW, const int* __restrict__ row_off,
        const int* __restrict__ sorted_rel, const float* __restrict__ sorted_s,
        const unsigned* __restrict__ smax_u, float* __restrict__ h) {
    int wave = threadIdx.x >> 6;
    int lane = threadIdx.x & 63;
    int n = blockIdx.x * 4 + wave;
    if (n >= N_NODES) return;
    int beg = row_off[n], end = row_off[n + 1];
    float smax = funmap(smax_u[n]);
    float l = 0.f;
    float2 acc = make_float2(0.f, 0.f);
    #pragma unroll 4
    for (int i = beg; i < end; ++i) {
        int r = sorted_rel[i];
        float p = __expf(sorted_s[i] - smax);
        float2 wv = ((const float2*)(RW + (size_t)r * HD))[lane];
        l += p;
        acc.x += p * wv.x;
        acc.y += p * wv.y;
    }
    float invl = (end > beg) ? 1.f / l : 0.f;
    ((float2*)(h + (size_t)n * HD))[lane] = make_float2(acc.x * invl, acc.y * invl);
}

// K7: per-column sum / sumsq over rows (block-partial -> global atomics)
__global__ __launch_bounds__(256) void k_stats(
        const float* __restrict__ Hout, float* __restrict__ colsum,
        float* __restrict__ colsumsq) {
    __shared__ float ls[256], lq[256];
    int t = threadIdx.x;
    int c = t & 127, half = t >> 7;
    int rbase = blockIdx.x * 64;
    float sum = 0.f, sq = 0.f;
    #pragma unroll 4
    for (int i = 0; i < 32; ++i) {
        int r = rbase + half + i * 2;
        float v = Hout[(size_t)r * HD + c];
        sum += v;
        sq += v * v;
    }
    ls[t] = sum;
    lq[t] = sq;
    __syncthreads();
    if (t < 128) {
        sum = ls[t] + ls[t + 128];
        sq = lq[t] + lq[t + 128];
        atomicAdd(colsum + c, sum);
        atomicAdd(colsumsq + c, sq);
    }
}

// K8: out = tanh((h - mean) * rstd * gamma + beta), in place on d_out
__global__ __launch_bounds__(256) void k_apply(
        float* __restrict__ Hout, const float* __restrict__ colsum,
        const float* __restrict__ colsumsq, const float* __restrict__ gamma,
        const float* __restrict__ beta) {
    int idx = blockIdx.x * 256 + threadIdx.x;  // float4 index
    if (idx >= N_NODES * HD / 4) return;
    int c0 = (idx * 4) & 127;
    float4 hv4 = ((const float4*)Hout)[idx];
    const float inv = 1.f / (float)N_NODES;
    float hv[4] = {hv4.x, hv4.y, hv4.z, hv4.w};
    float o[4];
    #pragma unroll
    for (int j = 0; j < 4; ++j) {
        int c = c0 + j;
        float mean = colsum[c] * inv;
        float var = colsumsq[c] * inv - mean * mean;
        float rstd = rsqrtf(var + BN_EPS);
        o[j] = tanhf((hv[j] - mean) * rstd * gamma[c] + beta[c]);
    }
    ((float4*)Hout)[idx] = make_float4(o[0], o[1], o[2], o[3]);
}

extern "C" void kernel_launch(void* const* d_in, const int* in_sizes, int n_in,
                              void* d_out, int out_size, void* d_ws, size_t ws_size,
                              hipStream_t stream) {
    const float* ent_emb  = (const float*)d_in[0];
    const float* rel_emb  = (const float*)d_in[1];
    const float* neigh_w  = (const float*)d_in[2];
    const float* bn_gamma = (const float*)d_in[3];
    const float* bn_beta  = (const float*)d_in[4];
    const int*   rel_id   = (const int*)d_in[5];
    const int*   dst      = (const int*)d_in[6];
    float* out = (float*)d_out;

    // workspace layout (4-byte units) — first 80256 words are memset to 0
    int*      counts     = (int*)d_ws;                    // [40000]
    float*    colsum     = (float*)d_ws + 40000;          // [128]
    float*    colsumsq   = (float*)d_ws + 40128;          // [128]
    unsigned* smax_u     = (unsigned*)d_ws + 40256;       // [40000]
    int*      row_off    = (int*)d_ws + 80256;            // [40001]
    int*      cursor     = (int*)d_ws + 120257;           // [40000]
    int*      sorted_rel = (int*)d_ws + 160257;           // [640000]
    int*      sorted_node= (int*)d_ws + 800257;           // [640000]
    float*    sorted_s   = (float*)d_ws + 1440257;        // [640000]
    float*    RW         = (float*)d_ws + 2080257;        // [474*128]
    int*      bsum       = (int*)d_ws + 2080257 + N_REL2 * HD;  // [NB_SCAN]

    hipMemsetAsync(d_ws, 0, (size_t)80256 * 4, stream);

    k_hist<<<(N_EDGES + 255) / 256, 256, 0, stream>>>(dst, counts);
    k_scan_part<<<NB_SCAN, 256, 0, stream>>>(counts, bsum);
    k_scan_top<<<1, 256, 0, stream>>>(bsum);
    k_scan_down<<<NB_SCAN, 256, 0, stream>>>(counts, bsum, row_off, cursor);
    k_sortrel<<<(N_EDGES + 255) / 256, 256, 0, stream>>>(dst, rel_id, cursor, sorted_rel, sorted_node);
    k_rw<<<N_REL2, 128, 0, stream>>>(rel_emb, neigh_w, RW);
    k_edge_dot<<<N_EDGES / 8, 256, 0, stream>>>(ent_emb, rel_emb, sorted_rel, sorted_node, sorted_s, smax_u);
    k_node<<<N_NODES / 4, 256, 0, stream>>>(RW, row_off, sorted_rel, sorted_s, smax_u, out);
    k_stats<<<N_NODES / 64, 256, 0, stream>>>(out, colsum, colsumsq);
    k_apply<<<N_NODES * HD / 4 / 256, 256, 0, stream>>>(out, colsum, colsumsq, bn_gamma, bn_beta);
}

// Round 5
// 212.357 us; speedup vs baseline: 1.1518x; 1.1518x over previous
//
#include <hip/hip_runtime.h>

#define N_NODES 40000
#define N_EDGES 640000
#define HD 128
#define N_REL2 474
#define BN_EPS 1e-5f
#define NB_SCAN ((N_NODES + 255) / 256)  // 157 scan blocks

// K1: histogram of edge destinations
__global__ __launch_bounds__(256) void k_hist(
        const int* __restrict__ dst, int* __restrict__ counts) {
    int e = blockIdx.x * 256 + threadIdx.x;
    if (e < N_EDGES) atomicAdd(counts + dst[e], 1);
}

// K2a: per-block sum of 256 counts
__global__ __launch_bounds__(256) void k_scan_part(
        const int* __restrict__ counts, int* __restrict__ bsum) {
    __shared__ int ls[256];
    int t = threadIdx.x;
    int idx = blockIdx.x * 256 + t;
    ls[t] = (idx < N_NODES) ? counts[idx] : 0;
    __syncthreads();
    #pragma unroll
    for (int off = 128; off > 0; off >>= 1) {
        if (t < off) ls[t] += ls[t + off];
        __syncthreads();
    }
    if (t == 0) bsum[blockIdx.x] = ls[0];
}

// K2b: per-block local scan; block offset from replicated top-level scan of bsum
__global__ __launch_bounds__(256) void k_scan_down(
        const int* __restrict__ counts, const int* __restrict__ bsum,
        int* __restrict__ row_off, int* __restrict__ cursor) {
    __shared__ int btop[256];
    __shared__ int ls[256];
    int t = threadIdx.x;
    // replicated top-level inclusive scan of the 157 block sums
    btop[t] = (t < NB_SCAN) ? bsum[t] : 0;
    __syncthreads();
    #pragma unroll
    for (int off = 1; off < 256; off <<= 1) {
        int tmp = (t >= off) ? btop[t - off] : 0;
        __syncthreads();
        btop[t] += tmp;
        __syncthreads();
    }
    int blockoff = (blockIdx.x == 0) ? 0 : btop[blockIdx.x - 1];
    // local scan of this block's 256 counts
    int idx = blockIdx.x * 256 + t;
    int v = (idx < N_NODES) ? counts[idx] : 0;
    ls[t] = v;
    __syncthreads();
    #pragma unroll
    for (int off = 1; off < 256; off <<= 1) {
        int tmp = (t >= off) ? ls[t - off] : 0;
        __syncthreads();
        ls[t] += tmp;
        __syncthreads();
    }
    int excl = ls[t] - v + blockoff;
    if (idx < N_NODES) {
        row_off[idx] = excl;
        cursor[idx] = excl;
    }
    if (idx == N_NODES) row_off[N_NODES] = N_EDGES;
}

// K3: scatter rel ids + node ids into CSR order
__global__ __launch_bounds__(256) void k_sortrel(
        const int* __restrict__ dst, const int* __restrict__ rel_id,
        int* __restrict__ cursor, int* __restrict__ sorted_rel,
        int* __restrict__ sorted_node) {
    int e = blockIdx.x * 256 + threadIdx.x;
    if (e < N_EDGES) {
        int d = dst[e];
        int p = atomicAdd(cursor + d, 1);
        sorted_rel[p] = rel_id[e];
        sorted_node[p] = d;
    }
}

// K4: RW = rel_emb @ neigh_w  (474 x 128 @ 128 x 128)
__global__ __launch_bounds__(128) void k_rw(
        const float* __restrict__ R, const float* __restrict__ W,
        float* __restrict__ RW) {
    __shared__ float row[HD];
    int r = blockIdx.x, c = threadIdx.x;
    row[c] = R[(size_t)r * HD + c];
    __syncthreads();
    float acc = 0.f;
    #pragma unroll 8
    for (int k = 0; k < HD; ++k) acc += row[k] * W[(size_t)k * HD + c];
    RW[(size_t)r * HD + c] = acc;
}

// K5: per-sorted-edge dot (32 lanes/edge), store only — NO atomics
__global__ __launch_bounds__(256) void k_edge_dot(
        const float* __restrict__ ent_emb, const float* __restrict__ R,
        const int* __restrict__ sorted_rel, const int* __restrict__ sorted_node,
        float* __restrict__ sorted_s) {
    int t = threadIdx.x;
    int e = blockIdx.x * 8 + (t >> 5);
    if (e >= N_EDGES) return;
    int lane = t & 31;
    int r = sorted_rel[e], n = sorted_node[e];
    float4 a = ((const float4*)(R + (size_t)r * HD))[lane];
    float4 b = ((const float4*)(ent_emb + (size_t)n * HD))[lane];
    float dot = a.x * b.x + a.y * b.y + a.z * b.z + a.w * b.w;
    #pragma unroll
    for (int m = 16; m >= 1; m >>= 1) dot += __shfl_xor(dot, m, 32);
    if (lane == 0) sorted_s[e] = dot;
}

// K6: one wave per node. Cooperative max over the node's contiguous s-segment,
//     then p=exp(s-m), l=sum p, acc = sum p_i * RW[r_i] via shfl broadcast.
__global__ __launch_bounds__(256) void k_node(
        const float* __restrict__ RW, const int* __restrict__ row_off,
        const int* __restrict__ sorted_rel, const float* __restrict__ sorted_s,
        float* __restrict__ h) {
    int wave = threadIdx.x >> 6;
    int lane = threadIdx.x & 63;
    int n = blockIdx.x * 4 + wave;
    if (n >= N_NODES) return;
    int beg = row_off[n], end = row_off[n + 1];
    float2 acc = make_float2(0.f, 0.f);
    float l = 0.f;
    if (end > beg) {
        // pass A: node max (one shfl-reduce per NODE)
        float mloc = -INFINITY;
        for (int base = beg; base < end; base += 64) {
            int i = base + lane;
            float sv = (i < end) ? sorted_s[i] : -INFINITY;
            mloc = fmaxf(mloc, sv);
        }
        #pragma unroll
        for (int msk = 32; msk >= 1; msk >>= 1)
            mloc = fmaxf(mloc, __shfl_xor(mloc, msk, 64));
        // pass B: accumulate
        for (int base = beg; base < end; base += 64) {
            int i = base + lane;
            int cnt = min(64, end - base);
            float p = 0.f;
            int r = 0;
            if (i < end) {
                p = __expf(sorted_s[i] - mloc);
                r = sorted_rel[i];
            }
            l += p;
            for (int j = 0; j < cnt; ++j) {
                float pj = __shfl(p, j, 64);
                int rj = __shfl(r, j, 64);
                float2 wv = ((const float2*)(RW + (size_t)rj * HD))[lane];
                acc.x += pj * wv.x;
                acc.y += pj * wv.y;
            }
        }
        #pragma unroll
        for (int msk = 32; msk >= 1; msk >>= 1) l += __shfl_xor(l, msk, 64);
    }
    float invl = (l > 0.f) ? 1.f / l : 0.f;
    ((float2*)(h + (size_t)n * HD))[lane] = make_float2(acc.x * invl, acc.y * invl);
}

// K7: per-column sum / sumsq over rows (block-partial -> global atomics)
__global__ __launch_bounds__(256) void k_stats(
        const float* __restrict__ Hout, float* __restrict__ colsum,
        float* __restrict__ colsumsq) {
    __shared__ float ls[256], lq[256];
    int t = threadIdx.x;
    int c = t & 127, half = t >> 7;
    int rbase = blockIdx.x * 64;
    float sum = 0.f, sq = 0.f;
    #pragma unroll 4
    for (int i = 0; i < 32; ++i) {
        int r = rbase + half + i * 2;
        float v = Hout[(size_t)r * HD + c];
        sum += v;
        sq += v * v;
    }
    ls[t] = sum;
    lq[t] = sq;
    __syncthreads();
    if (t < 128) {
        sum = ls[t] + ls[t + 128];
        sq = lq[t] + lq[t + 128];
        atomicAdd(colsum + c, sum);
        atomicAdd(colsumsq + c, sq);
    }
}

// K8: out = tanh((h - mean) * rstd * gamma + beta), in place on d_out
__global__ __launch_bounds__(256) void k_apply(
        float* __restrict__ Hout, const float* __restrict__ colsum,
        const float* __restrict__ colsumsq, const float* __restrict__ gamma,
        const float* __restrict__ beta) {
    int idx = blockIdx.x * 256 + threadIdx.x;  // float4 index
    if (idx >= N_NODES * HD / 4) return;
    int c0 = (idx * 4) & 127;
    float4 hv4 = ((const float4*)Hout)[idx];
    const float inv = 1.f / (float)N_NODES;
    float hv[4] = {hv4.x, hv4.y, hv4.z, hv4.w};
    float o[4];
    #pragma unroll
    for (int j = 0; j < 4; ++j) {
        int c = c0 + j;
        float mean = colsum[c] * inv;
        float var = colsumsq[c] * inv - mean * mean;
        float rstd = rsqrtf(var + BN_EPS);
        o[j] = tanhf((hv[j] - mean) * rstd * gamma[c] + beta[c]);
    }
    ((float4*)Hout)[idx] = make_float4(o[0], o[1], o[2], o[3]);
}

extern "C" void kernel_launch(void* const* d_in, const int* in_sizes, int n_in,
                              void* d_out, int out_size, void* d_ws, size_t ws_size,
                              hipStream_t stream) {
    const float* ent_emb  = (const float*)d_in[0];
    const float* rel_emb  = (const float*)d_in[1];
    const float* neigh_w  = (const float*)d_in[2];
    const float* bn_gamma = (const float*)d_in[3];
    const float* bn_beta  = (const float*)d_in[4];
    const int*   rel_id   = (const int*)d_in[5];
    const int*   dst      = (const int*)d_in[6];
    float* out = (float*)d_out;

    // workspace layout (4-byte units) — first 40256 words are memset to 0
    int*      counts     = (int*)d_ws;                    // [40000]
    float*    colsum     = (float*)d_ws + 40000;          // [128]
    float*    colsumsq   = (float*)d_ws + 40128;          // [128]
    int*      row_off    = (int*)d_ws + 40256;            // [40001]
    int*      cursor     = (int*)d_ws + 80257;            // [40000]
    int*      sorted_rel = (int*)d_ws + 120257;           // [640000]
    int*      sorted_node= (int*)d_ws + 760257;           // [640000]
    float*    sorted_s   = (float*)d_ws + 1400257;        // [640000]
    float*    RW         = (float*)d_ws + 2040257;        // [474*128]
    int*      bsum       = (int*)d_ws + 2040257 + N_REL2 * HD;  // [NB_SCAN]

    hipMemsetAsync(d_ws, 0, (size_t)40256 * 4, stream);

    k_hist<<<(N_EDGES + 255) / 256, 256, 0, stream>>>(dst, counts);
    k_scan_part<<<NB_SCAN, 256, 0, stream>>>(counts, bsum);
    k_scan_down<<<NB_SCAN, 256, 0, stream>>>(counts, bsum, row_off, cursor);
    k_sortrel<<<(N_EDGES + 255) / 256, 256, 0, stream>>>(dst, rel_id, cursor, sorted_rel, sorted_node);
    k_rw<<<N_REL2, 128, 0, stream>>>(rel_emb, neigh_w, RW);
    k_edge_dot<<<N_EDGES / 8, 256, 0, stream>>>(ent_emb, rel_emb, sorted_rel, sorted_node, sorted_s);
    k_node<<<N_NODES / 4, 256, 0, stream>>>(RW, row_off, sorted_rel, sorted_s, out);
    k_stats<<<N_NODES / 64, 256, 0, stream>>>(out, colsum, colsumsq);
    k_apply<<<N_NODES * HD / 4 / 256, 256, 0, stream>>>(out, colsum, colsumsq, bn_gamma, bn_beta);
}